// Round 6
// baseline (153.543 us; speedup 1.0000x reference)
//
#include <hip/hip_runtime.h>

// PGNN: N=50000 nodes, K=32 anchors/edges per node, E=1.6M edges
// out: normalize(out_position)[N,32] f32
constexpr int NN = 50000;
constexpr int KANCH = 32;

typedef __attribute__((ext_vector_type(8))) short bfrag;   // 8 bf16 (4 VGPR)
typedef __attribute__((ext_vector_type(4))) float ffrag;   // 4 f32 acc

static __device__ __forceinline__ float bf2f(unsigned short u) {
    return __uint_as_float(((unsigned int)u) << 16);
}
static __device__ __forceinline__ unsigned short f2bf(float f) {
    unsigned int x = __float_as_uint(f);
    x += 0x7FFFu + ((x >> 16) & 1u);   // round-to-nearest-even
    return (unsigned short)(x >> 16);
}

// ---------------------------------------------------------------------------
// K0: compose layer-1 weights through the pre-linear; pack weights to bf16.
// ---------------------------------------------------------------------------
__global__ __launch_bounds__(256) void k_prep(
    const float* __restrict__ w_pre, const float* __restrict__ b_pre,
    const float* __restrict__ Wu1, const float* __restrict__ bu1,
    const float* __restrict__ Wv1, const float* __restrict__ bv1,
    const float* __restrict__ Wu2, const float* __restrict__ bu2,
    const float* __restrict__ Wv2, const float* __restrict__ bv2,
    unsigned short* __restrict__ wcat1, float* __restrict__ bias1,
    unsigned short* __restrict__ wcat2, float* __restrict__ bias2)
{
    int gid = blockIdx.x * 256 + threadIdx.x;
    if (gid < 16384) {
        int j = gid >> 7, i = gid & 127;
        const float* Wr = (j < 64) ? (Wu1 + j * 64) : (Wv1 + (j - 64) * 64);
        float a = 0.f;
        for (int t = 0; t < 64; ++t) a += Wr[t] * w_pre[t * 128 + i];
        wcat1[gid] = f2bf(a);
    } else if (gid < 16384 + 4096) {
        int g = gid - 16384;
        int j = g >> 6, i = g & 63;
        float w = (j < 32) ? Wu2[j * 64 + i] : Wv2[(j - 32) * 64 + i];
        wcat2[g] = f2bf(w);
    } else if (gid < 16384 + 4096 + 128) {
        int j = gid - (16384 + 4096);
        const float* Wr = (j < 64) ? (Wu1 + j * 64) : (Wv1 + (j - 64) * 64);
        float a = (j < 64) ? bu1[j] : bv1[j - 64];
        for (int t = 0; t < 64; ++t) a += Wr[t] * b_pre[t];
        bias1[j] = a;
    } else if (gid < 16384 + 4096 + 128 + 64) {
        int j = gid - (16384 + 4096 + 128);
        bias2[j] = (j < 32) ? bu2[j] : bv2[j - 32];
    }
}

// ---------------------------------------------------------------------------
// K1: layer-1 u/v linears via MFMA, writing SLICE-MAJOR bf16 tables
// u1s/v1s[slice][NN][16] (slice s = output dims s*16..s*16+15).
// A (feat f32) split in-register into bf16 hi+lo (exact; 2 MFMAs per step).
// ---------------------------------------------------------------------------
__global__ __launch_bounds__(256) void k_gemm1(
    const float* __restrict__ feat,            // [NN][128]
    const unsigned short* __restrict__ wcat,   // [128][128] bf16
    const float* __restrict__ bias,            // [128] f32
    unsigned short* __restrict__ u1s,          // [4][NN][16] bf16
    unsigned short* __restrict__ v1s,          // [4][NN][16] bf16
    int nTiles)                                // NN/16
{
    __shared__ unsigned short s_w[128 * 136];  // 272 B row stride
    __shared__ float s_b[128];
    int tid = threadIdx.x;
    for (int idx = tid; idx < 128 * 16; idx += 256) {
        int r = idx >> 4, c8 = idx & 15;
        const uint4* g = reinterpret_cast<const uint4*>(wcat + r * 128 + c8 * 8);
        *reinterpret_cast<uint4*>(&s_w[r * 136 + c8 * 8]) = *g;
    }
    if (tid < 128) s_b[tid] = bias[tid];
    __syncthreads();

    int wv = __builtin_amdgcn_readfirstlane(tid >> 6);
    int lane = tid & 63;
    int col = lane & 15;        // A row (node) / D col (out) / W row
    int grp = lane >> 4;        // k-subchunk 0..3
    int slot = blockIdx.x * 4 + wv;
    int stride = gridDim.x * 4;
    for (int tile = slot; tile < nTiles; tile += stride) {
        int n0 = tile * 16;
        const float* fp = feat + (size_t)(n0 + col) * 128 + grp * 8;
        bfrag AH[4], AL[4];
#pragma unroll
        for (int s = 0; s < 4; ++s) {
            float4 p0 = *reinterpret_cast<const float4*>(fp + s * 32);
            float4 p1 = *reinterpret_cast<const float4*>(fp + s * 32 + 4);
            float a8[8] = {p0.x, p0.y, p0.z, p0.w, p1.x, p1.y, p1.z, p1.w};
#pragma unroll
            for (int e = 0; e < 8; ++e) {
                unsigned short hb = f2bf(a8[e]);
                AH[s][e] = (short)hb;
                AL[s][e] = (short)f2bf(a8[e] - bf2f(hb));
            }
        }
#pragma unroll
        for (int t = 0; t < 8; ++t) {
            ffrag a = {0.f, 0.f, 0.f, 0.f};
#pragma unroll
            for (int s = 0; s < 4; ++s) {
                const bfrag w = *reinterpret_cast<const bfrag*>(
                    &s_w[(t * 16 + col) * 136 + s * 32 + grp * 8]);
                a = __builtin_amdgcn_mfma_f32_16x16x32_bf16(AH[s], w, a, 0, 0, 0);
                a = __builtin_amdgcn_mfma_f32_16x16x32_bf16(AL[s], w, a, 0, 0, 0);
            }
            float bb = s_b[t * 16 + col];
#pragma unroll
            for (int j = 0; j < 4; ++j) {
                int node = n0 + grp * 4 + j;
                unsigned short o = f2bf(a[j] + bb);
                if (t < 4) u1s[((size_t)t * NN + node) * 16 + col] = o;
                else       v1s[((size_t)(t - 4) * NN + node) * 16 + col] = o;
            }
        }
    }
}

// ---------------------------------------------------------------------------
// K2: layer-1 aggregation over ONE 16-dim slice. Per-pass gather working set
// = 2 x 1.6 MB table slices -> L2-resident per XCD (4 MiB). Index loads are
// plain CACHED vectorized loads (int2/float2 per lane, es-major) — round-4's
// nt scalar loads caused ~16x line amplification; that was the regression.
// lane = (eg=lane>>2: edge group owning edges eg*2,eg*2+1; c=lane&3: 8-B
// chunk of the 32-B slice row). Reduce over eg via 4 shfl_xor.
// ---------------------------------------------------------------------------
__global__ __launch_bounds__(256) void k_gather1s(
    const ushort4* __restrict__ u1s, const ushort4* __restrict__ v1s, // [4][NN][4]
    const int* __restrict__ src, const int* __restrict__ dst,
    const float* __restrict__ dists, ushort4* __restrict__ x2v,      // [NN][16]
    int slice)
{
    int tid = threadIdx.x;
    int wv = __builtin_amdgcn_readfirstlane(tid >> 6);
    int lane = tid & 63;
    int c = lane & 3;       // slice dims 4c..4c+3
    int eg = lane >> 2;     // edge group 0..15
    int slot = blockIdx.x * 4 + wv;
    int stride = gridDim.x * 4;
    const ushort4* us = u1s + (size_t)slice * NN * 4;
    const ushort4* vs = v1s + (size_t)slice * NN * 4;
    for (int n = slot; n < NN; n += stride) {
        int base = n * KANCH + eg * 2;
        int2   s2 = *reinterpret_cast<const int2*>(src + base);
        int2   d2 = *reinterpret_cast<const int2*>(dst + base);
        float2 p2 = *reinterpret_cast<const float2*>(dists + base);
        ushort4 u0 = us[(size_t)s2.x * 4 + c];
        ushort4 u1 = us[(size_t)s2.y * 4 + c];
        ushort4 v0 = vs[(size_t)d2.x * 4 + c];
        ushort4 v1 = vs[(size_t)d2.y * 4 + c];
        float a0 = fmaxf(fmaf(bf2f(u0.x), p2.x, bf2f(v0.x)), 0.f)
                 + fmaxf(fmaf(bf2f(u1.x), p2.y, bf2f(v1.x)), 0.f);
        float a1 = fmaxf(fmaf(bf2f(u0.y), p2.x, bf2f(v0.y)), 0.f)
                 + fmaxf(fmaf(bf2f(u1.y), p2.y, bf2f(v1.y)), 0.f);
        float a2 = fmaxf(fmaf(bf2f(u0.z), p2.x, bf2f(v0.z)), 0.f)
                 + fmaxf(fmaf(bf2f(u1.z), p2.y, bf2f(v1.z)), 0.f);
        float a3 = fmaxf(fmaf(bf2f(u0.w), p2.x, bf2f(v0.w)), 0.f)
                 + fmaxf(fmaf(bf2f(u1.w), p2.y, bf2f(v1.w)), 0.f);
        // reduce over the 16 edge groups (lane bits 2..5)
        a0 += __shfl_xor(a0, 4); a0 += __shfl_xor(a0, 8);
        a0 += __shfl_xor(a0, 16); a0 += __shfl_xor(a0, 32);
        a1 += __shfl_xor(a1, 4); a1 += __shfl_xor(a1, 8);
        a1 += __shfl_xor(a1, 16); a1 += __shfl_xor(a1, 32);
        a2 += __shfl_xor(a2, 4); a2 += __shfl_xor(a2, 8);
        a2 += __shfl_xor(a2, 16); a2 += __shfl_xor(a2, 32);
        a3 += __shfl_xor(a3, 4); a3 += __shfl_xor(a3, 8);
        a3 += __shfl_xor(a3, 16); a3 += __shfl_xor(a3, 32);
        if (lane < 4) {
            ushort4 r;
            r.x = f2bf(a0 * 0.03125f); r.y = f2bf(a1 * 0.03125f);
            r.z = f2bf(a2 * 0.03125f); r.w = f2bf(a3 * 0.03125f);
            x2v[(size_t)n * 16 + slice * 4 + lane] = r;   // dims slice*16+c*4..+3
        }
    }
}

// ---------------------------------------------------------------------------
// K3: layer-2 u/v linears via MFMA.  [50000,64] bf16 @ [64,64]ᵀ bf16.
// ---------------------------------------------------------------------------
__global__ __launch_bounds__(256) void k_gemm2(
    const unsigned short* __restrict__ x2b,    // [NN][64] bf16
    const unsigned short* __restrict__ wcat,   // [64][64] bf16
    const float* __restrict__ bias,            // [64] f32
    unsigned short* __restrict__ ub,           // [NN][32] bf16
    unsigned short* __restrict__ vb,           // [NN][32] bf16
    int nTiles)
{
    __shared__ unsigned short s_w[64 * 72];
    __shared__ float s_b[64];
    int tid = threadIdx.x;
    for (int idx = tid; idx < 64 * 8; idx += 256) {
        int r = idx >> 3, c8 = idx & 7;
        const uint4* g = reinterpret_cast<const uint4*>(wcat + r * 64 + c8 * 8);
        *reinterpret_cast<uint4*>(&s_w[r * 72 + c8 * 8]) = *g;
    }
    if (tid < 64) s_b[tid] = bias[tid];
    __syncthreads();

    int wv = __builtin_amdgcn_readfirstlane(tid >> 6);
    int lane = tid & 63;
    int col = lane & 15;
    int grp = lane >> 4;
    int slot = blockIdx.x * 4 + wv;
    int stride = gridDim.x * 4;
    for (int tile = slot; tile < nTiles; tile += stride) {
        int n0 = tile * 16;
        bfrag A[2];
#pragma unroll
        for (int s = 0; s < 2; ++s) {
            uint4 raw = *reinterpret_cast<const uint4*>(
                x2b + (size_t)(n0 + col) * 64 + s * 32 + grp * 8);
            A[s] = *reinterpret_cast<const bfrag*>(&raw);
        }
#pragma unroll
        for (int t = 0; t < 4; ++t) {
            ffrag a = {0.f, 0.f, 0.f, 0.f};
#pragma unroll
            for (int s = 0; s < 2; ++s) {
                const bfrag w = *reinterpret_cast<const bfrag*>(
                    &s_w[(t * 16 + col) * 72 + s * 32 + grp * 8]);
                a = __builtin_amdgcn_mfma_f32_16x16x32_bf16(A[s], w, a, 0, 0, 0);
            }
            float bb = s_b[t * 16 + col];
#pragma unroll
            for (int j = 0; j < 4; ++j) {
                int node = n0 + grp * 4 + j;
                unsigned short o = f2bf(a[j] + bb);
                if (t < 2) ub[(size_t)node * 32 + t * 16 + col] = o;
                else       vb[(size_t)node * 32 + (t - 2) * 16 + col] = o;
            }
        }
    }
}

// ---------------------------------------------------------------------------
// K4: layer-2 message + position dot + L2 normalize (round-5 verified).
// Wave handles TWO nodes per iter; lane = (es=lane>>3, c=lane&7).
// ---------------------------------------------------------------------------
__global__ __launch_bounds__(256, 4) void k_out(
    const ushort4* __restrict__ u2v, const ushort4* __restrict__ v2v, // [NN*8]
    const int* __restrict__ src, const int* __restrict__ dst,
    const float* __restrict__ dists, const float* __restrict__ wp2,
    const float* __restrict__ bp2, float* __restrict__ out)
{
    int tid = threadIdx.x;
    int wv = __builtin_amdgcn_readfirstlane(tid >> 6);
    int lane = tid & 63;
    int c = lane & 7;       // dims 4c..4c+3
    int es = lane >> 3;     // edge subgroup 0..7 (k = es*4 + kk)
    int slot = blockIdx.x * 4 + wv;
    int stride = gridDim.x * 4;
    float4 w4 = reinterpret_cast<const float4*>(wp2)[c];
    float bp = bp2[0];
    const int nPairs = NN / 2;
    for (int p = slot; p < nPairs; p += stride) {
        int nA = p * 2, nB = nA + 1;
        int baseA = nA * KANCH, baseB = nB * KANCH;
        int4   sA = *reinterpret_cast<const int4*>(src + baseA + es * 4);
        int4   dA = *reinterpret_cast<const int4*>(dst + baseA + es * 4);
        float4 pA = *reinterpret_cast<const float4*>(dists + baseA + es * 4);
        int4   sB = *reinterpret_cast<const int4*>(src + baseB + es * 4);
        int4   dB = *reinterpret_cast<const int4*>(dst + baseB + es * 4);
        float4 pB = *reinterpret_cast<const float4*>(dists + baseB + es * 4);
        ushort4 uA[4], vA[4], uB[4], vB[4];
        uA[0] = u2v[(size_t)sA.x * 8 + c]; uA[1] = u2v[(size_t)sA.y * 8 + c];
        uA[2] = u2v[(size_t)sA.z * 8 + c]; uA[3] = u2v[(size_t)sA.w * 8 + c];
        vA[0] = v2v[(size_t)dA.x * 8 + c]; vA[1] = v2v[(size_t)dA.y * 8 + c];
        vA[2] = v2v[(size_t)dA.z * 8 + c]; vA[3] = v2v[(size_t)dA.w * 8 + c];
        uB[0] = u2v[(size_t)sB.x * 8 + c]; uB[1] = u2v[(size_t)sB.y * 8 + c];
        uB[2] = u2v[(size_t)sB.z * 8 + c]; uB[3] = u2v[(size_t)sB.w * 8 + c];
        vB[0] = v2v[(size_t)dB.x * 8 + c]; vB[1] = v2v[(size_t)dB.y * 8 + c];
        vB[2] = v2v[(size_t)dB.z * 8 + c]; vB[3] = v2v[(size_t)dB.w * 8 + c];
        float spA[4] = {pA.x, pA.y, pA.z, pA.w};
        float spB[4] = {pB.x, pB.y, pB.z, pB.w};
        float qA[4], qB[4];
#pragma unroll
        for (int kk = 0; kk < 4; ++kk) {
            float pa, pb;
            pa  = fmaxf(fmaf(bf2f(uA[kk].x), spA[kk], bf2f(vA[kk].x)), 0.f) * w4.x;
            pa += fmaxf(fmaf(bf2f(uA[kk].y), spA[kk], bf2f(vA[kk].y)), 0.f) * w4.y;
            pa += fmaxf(fmaf(bf2f(uA[kk].z), spA[kk], bf2f(vA[kk].z)), 0.f) * w4.z;
            pa += fmaxf(fmaf(bf2f(uA[kk].w), spA[kk], bf2f(vA[kk].w)), 0.f) * w4.w;
            pb  = fmaxf(fmaf(bf2f(uB[kk].x), spB[kk], bf2f(vB[kk].x)), 0.f) * w4.x;
            pb += fmaxf(fmaf(bf2f(uB[kk].y), spB[kk], bf2f(vB[kk].y)), 0.f) * w4.y;
            pb += fmaxf(fmaf(bf2f(uB[kk].z), spB[kk], bf2f(vB[kk].z)), 0.f) * w4.z;
            pb += fmaxf(fmaf(bf2f(uB[kk].w), spB[kk], bf2f(vB[kk].w)), 0.f) * w4.w;
            pa += __shfl_xor(pa, 1); pa += __shfl_xor(pa, 2); pa += __shfl_xor(pa, 4);
            pb += __shfl_xor(pb, 1); pb += __shfl_xor(pb, 2); pb += __shfl_xor(pb, 4);
            qA[kk] = pa; qB[kk] = pb;
        }
        int t = lane & 31;
        int srcl = (t >> 2) * 8;
        float cA0 = __shfl(qA[0], srcl), cA1 = __shfl(qA[1], srcl);
        float cA2 = __shfl(qA[2], srcl), cA3 = __shfl(qA[3], srcl);
        float cB0 = __shfl(qB[0], srcl), cB1 = __shfl(qB[1], srcl);
        float cB2 = __shfl(qB[2], srcl), cB3 = __shfl(qB[3], srcl);
        int ks = t & 3;
        float qa = (ks == 0) ? cA0 : (ks == 1) ? cA1 : (ks == 2) ? cA2 : cA3;
        float qb = (ks == 0) ? cB0 : (ks == 1) ? cB1 : (ks == 2) ? cB2 : cB3;
        float q = ((lane < 32) ? qa : qb) + bp;
        float ss = q * q;
#pragma unroll
        for (int off = 16; off >= 1; off >>= 1)
            ss += __shfl_xor(ss, off);     // stays within each 32-lane half
        float den = fmaxf(sqrtf(ss), 1e-12f);
        float o = q / den;
        if (lane < 32) out[(size_t)nA * KANCH + t] = o;
        else           out[(size_t)nB * KANCH + t] = o;
    }
}

// ---------------------------------------------------------------------------
extern "C" void kernel_launch(void* const* d_in, const int* in_sizes, int n_in,
                              void* d_out, int out_size, void* d_ws, size_t ws_size,
                              hipStream_t stream)
{
    const float* feat  = (const float*)d_in[0];
    const float* dists = (const float*)d_in[1];
    const int*   src   = (const int*)d_in[2];
    const int*   dst   = (const int*)d_in[3];
    const float* w_pre = (const float*)d_in[4];
    const float* b_pre = (const float*)d_in[5];
    const float* Wu1   = (const float*)d_in[6];
    const float* bu1   = (const float*)d_in[7];
    const float* Wv1   = (const float*)d_in[8];
    const float* bv1   = (const float*)d_in[9];
    // d_in[10]=wp1, d_in[11]=bp1: layer-1 position output is discarded
    const float* Wu2   = (const float*)d_in[12];
    const float* bu2   = (const float*)d_in[13];
    const float* Wv2   = (const float*)d_in[14];
    const float* bv2   = (const float*)d_in[15];
    const float* wp2   = (const float*)d_in[16];
    const float* bp2   = (const float*)d_in[17];
    float* out = (float*)d_out;

    // workspace (~19.3 MB)
    unsigned short* wcat1 = (unsigned short*)d_ws;           // 16384 us
    float* bias1 = (float*)(wcat1 + 16384);                  // 128 f
    unsigned short* wcat2 = (unsigned short*)(bias1 + 128);  // 4096 us
    float* bias2 = (float*)(wcat2 + 4096);                   // 64 f
    unsigned short* u1s = (unsigned short*)(bias2 + 64);     // [4][NN][16]
    unsigned short* v1s = u1s + (size_t)NN * 64;             // [4][NN][16]
    unsigned short* x2b = v1s + (size_t)NN * 64;             // [NN][64]
    unsigned short* u2b = u1s;   // alias: u1s dead after gather passes
    unsigned short* v2b = v1s;   // alias: v1s dead after gather passes

    k_prep<<<81, 256, 0, stream>>>(w_pre, b_pre, Wu1, bu1, Wv1, bv1,
                                   Wu2, bu2, Wv2, bv2,
                                   wcat1, bias1, wcat2, bias2);
    k_gemm1<<<782, 256, 0, stream>>>(feat, wcat1, bias1, u1s, v1s, NN / 16);
    for (int s = 0; s < 4; ++s)
        k_gather1s<<<2048, 256, 0, stream>>>((const ushort4*)u1s, (const ushort4*)v1s,
                                             src, dst, dists, (ushort4*)x2b, s);
    k_gemm2<<<782, 256, 0, stream>>>(x2b, wcat2, bias2, u2b, v2b, NN / 16);
    k_out<<<2048, 256, 0, stream>>>((const ushort4*)u2b, (const ushort4*)v2b,
                                    src, dst, dists, wp2, bp2, out);
}

// Round 7
// 117.640 us; speedup vs baseline: 1.3052x; 1.3052x over previous
//
#include <hip/hip_runtime.h>

// PGNN: N=50000 nodes, K=32 anchors/edges per node, E=1.6M edges
// out: normalize(out_position)[N,32] f32
constexpr int NN = 50000;
constexpr int KANCH = 32;

typedef __attribute__((ext_vector_type(8))) short bfrag;   // 8 bf16 (4 VGPR)
typedef __attribute__((ext_vector_type(4))) float ffrag;   // 4 f32 acc

static __device__ __forceinline__ float bf2f(unsigned short u) {
    return __uint_as_float(((unsigned int)u) << 16);
}
static __device__ __forceinline__ unsigned short f2bf(float f) {
    unsigned int x = __float_as_uint(f);
    x += 0x7FFFu + ((x >> 16) & 1u);   // round-to-nearest-even
    return (unsigned short)(x >> 16);
}

// ---------------------------------------------------------------------------
// K0: compose layer-1 weights through the pre-linear; pack to bf16.
// wcat1[j][i] = bf16( (Wu1|Wv1) @ w_pre )  [128][128]
// bias1[j]   = (Wu1|Wv1)@b_pre + (bu1|bv1)
// ---------------------------------------------------------------------------
__global__ __launch_bounds__(256) void k_prep(
    const float* __restrict__ w_pre, const float* __restrict__ b_pre,
    const float* __restrict__ Wu1, const float* __restrict__ bu1,
    const float* __restrict__ Wv1, const float* __restrict__ bv1,
    unsigned short* __restrict__ wcat1, float* __restrict__ bias1)
{
    int gid = blockIdx.x * 256 + threadIdx.x;
    if (gid < 16384) {
        int j = gid >> 7, i = gid & 127;
        const float* Wr = (j < 64) ? (Wu1 + j * 64) : (Wv1 + (j - 64) * 64);
        float a = 0.f;
        for (int t = 0; t < 64; ++t) a += Wr[t] * w_pre[t * 128 + i];
        wcat1[gid] = f2bf(a);
    } else if (gid < 16384 + 128) {
        int j = gid - 16384;
        const float* Wr = (j < 64) ? (Wu1 + j * 64) : (Wv1 + (j - 64) * 64);
        float a = (j < 64) ? bu1[j] : bv1[j - 64];
        for (int t = 0; t < 64; ++t) a += Wr[t] * b_pre[t];
        bias1[j] = a;
    }
}

// ---------------------------------------------------------------------------
// K1: layer-1 u/v linears via MFMA.  [NN][64] bf16 tables (round-5 verified).
// A (feat f32) split in-register into bf16 hi+lo (exact; 2 MFMAs per step).
// ---------------------------------------------------------------------------
__global__ __launch_bounds__(256) void k_gemm1(
    const float* __restrict__ feat,            // [NN][128]
    const unsigned short* __restrict__ wcat,   // [128][128] bf16
    const float* __restrict__ bias,            // [128] f32
    unsigned short* __restrict__ ub,           // [NN][64] bf16
    unsigned short* __restrict__ vb,           // [NN][64] bf16
    int nTiles)                                // NN/16
{
    __shared__ unsigned short s_w[128 * 136];  // 272 B row stride
    __shared__ float s_b[128];
    int tid = threadIdx.x;
    for (int idx = tid; idx < 128 * 16; idx += 256) {
        int r = idx >> 4, c8 = idx & 15;
        const uint4* g = reinterpret_cast<const uint4*>(wcat + r * 128 + c8 * 8);
        *reinterpret_cast<uint4*>(&s_w[r * 136 + c8 * 8]) = *g;
    }
    if (tid < 128) s_b[tid] = bias[tid];
    __syncthreads();

    int wv = __builtin_amdgcn_readfirstlane(tid >> 6);
    int lane = tid & 63;
    int col = lane & 15;        // A row (node) / D col (out) / W row
    int grp = lane >> 4;        // k-subchunk 0..3
    int slot = blockIdx.x * 4 + wv;
    int stride = gridDim.x * 4;
    for (int tile = slot; tile < nTiles; tile += stride) {
        int n0 = tile * 16;
        const float* fp = feat + (size_t)(n0 + col) * 128 + grp * 8;
        bfrag AH[4], AL[4];
#pragma unroll
        for (int s = 0; s < 4; ++s) {
            float4 p0 = *reinterpret_cast<const float4*>(fp + s * 32);
            float4 p1 = *reinterpret_cast<const float4*>(fp + s * 32 + 4);
            float a8[8] = {p0.x, p0.y, p0.z, p0.w, p1.x, p1.y, p1.z, p1.w};
#pragma unroll
            for (int e = 0; e < 8; ++e) {
                unsigned short hb = f2bf(a8[e]);
                AH[s][e] = (short)hb;
                AL[s][e] = (short)f2bf(a8[e] - bf2f(hb));
            }
        }
#pragma unroll
        for (int t = 0; t < 8; ++t) {
            ffrag a = {0.f, 0.f, 0.f, 0.f};
#pragma unroll
            for (int s = 0; s < 4; ++s) {
                const bfrag w = *reinterpret_cast<const bfrag*>(
                    &s_w[(t * 16 + col) * 136 + s * 32 + grp * 8]);
                a = __builtin_amdgcn_mfma_f32_16x16x32_bf16(AH[s], w, a, 0, 0, 0);
                a = __builtin_amdgcn_mfma_f32_16x16x32_bf16(AL[s], w, a, 0, 0, 0);
            }
            float bb = s_b[t * 16 + col];
#pragma unroll
            for (int j = 0; j < 4; ++j) {
                int node = n0 + grp * 4 + j;
                unsigned short o = f2bf(a[j] + bb);
                if (t < 4) ub[(size_t)node * 64 + t * 16 + col] = o;
                else       vb[(size_t)node * 64 + (t - 4) * 16 + col] = o;
            }
        }
    }
}

// ---------------------------------------------------------------------------
// K2: FUSED layer-1 aggregation + layer-2 u/v matvec.
// Gather (round-3 verified structure): wave-per-node, lane=(es=lane>>4,
// c=lane&15), ushort4 row reads (4 rows x 128B / instr), shfl reduce.
// Then, with x2[n] (64 f32) in the wave: 64x64 matvec in-register.
// Lane j holds output column W'[.][j] in 64 VGPRs (preloaded once);
// x2 staged in wave-private LDS (256 B), read back as broadcasts.
// Writes u2/v2 bf16 tables directly -- no x2 round-trip, no gemm2 kernel.
// ---------------------------------------------------------------------------
__global__ __launch_bounds__(256) void k_fuse(
    const ushort4* __restrict__ u1v, const ushort4* __restrict__ v1v, // [NN*16]
    const int* __restrict__ src, const int* __restrict__ dst,
    const float* __restrict__ dists,
    const float* __restrict__ Wu2, const float* __restrict__ bu2,
    const float* __restrict__ Wv2, const float* __restrict__ bv2,
    unsigned short* __restrict__ u2b,          // [NN][32] bf16
    unsigned short* __restrict__ v2b)          // [NN][32] bf16
{
    __shared__ float s_x2[4 * 64];             // per-wave x2 staging
    int tid = threadIdx.x;
    int wv = __builtin_amdgcn_readfirstlane(tid >> 6);
    int lane = tid & 63;
    // ---- one-time: preload this lane's output column of W' = [Wu2|Wv2] ----
    const float* wrow = (lane < 32) ? (Wu2 + lane * 64) : (Wv2 + (lane - 32) * 64);
    float wcol[64];
#pragma unroll
    for (int i4 = 0; i4 < 16; ++i4) {
        float4 t = *reinterpret_cast<const float4*>(wrow + i4 * 4);
        wcol[i4 * 4 + 0] = t.x; wcol[i4 * 4 + 1] = t.y;
        wcol[i4 * 4 + 2] = t.z; wcol[i4 * 4 + 3] = t.w;
    }
    float bj = (lane < 32) ? bu2[lane] : bv2[lane - 32];

    int c = lane & 15;      // dims 4c..4c+3
    int es = lane >> 4;     // edge subgroup 0..3
    int slot = blockIdx.x * 4 + wv;
    int stride = gridDim.x * 4;
    float* sx = &s_x2[wv * 64];
    for (int n = slot; n < NN; n += stride) {
        int base = n * KANCH;
        float a0 = 0.f, a1 = 0.f, a2 = 0.f, a3 = 0.f;
#pragma unroll 4
        for (int kk = 0; kk < 8; ++kk) {
            int k = kk * 4 + es;
            int sk = src[base + k];
            int dk = dst[base + k];
            float sp = dists[base + k];
            ushort4 uu = u1v[(size_t)sk * 16 + c];
            ushort4 vv = v1v[(size_t)dk * 16 + c];
            a0 += fmaxf(fmaf(bf2f(uu.x), sp, bf2f(vv.x)), 0.f);
            a1 += fmaxf(fmaf(bf2f(uu.y), sp, bf2f(vv.y)), 0.f);
            a2 += fmaxf(fmaf(bf2f(uu.z), sp, bf2f(vv.z)), 0.f);
            a3 += fmaxf(fmaf(bf2f(uu.w), sp, bf2f(vv.w)), 0.f);
        }
        // reduce the 4 edge-subgroups (lanes ^16, ^32)
        a0 += __shfl_xor(a0, 16); a0 += __shfl_xor(a0, 32);
        a1 += __shfl_xor(a1, 16); a1 += __shfl_xor(a1, 32);
        a2 += __shfl_xor(a2, 16); a2 += __shfl_xor(a2, 32);
        a3 += __shfl_xor(a3, 16); a3 += __shfl_xor(a3, 32);
        if (lane < 16) {
            float4 r;
            r.x = a0 * 0.03125f; r.y = a1 * 0.03125f;
            r.z = a2 * 0.03125f; r.w = a3 * 0.03125f;
            *reinterpret_cast<float4*>(sx + c * 4) = r;   // wave-private LDS
        }
        // ---- fused 64x64 matvec: acc_j = bj + sum_i x2[i] * W'[i][j] ----
        float acc = bj;
#pragma unroll
        for (int i = 0; i < 64; ++i)
            acc = fmaf(sx[i], wcol[i], acc);   // sx[i]: broadcast read
        unsigned short o = f2bf(acc);
        if (lane < 32) u2b[(size_t)n * 32 + lane] = o;
        else           v2b[(size_t)n * 32 + (lane - 32)] = o;
    }
}

// ---------------------------------------------------------------------------
// K3: layer-2 message + position dot + L2 normalize (round-5 verified).
// Wave handles TWO nodes per iter; lane = (es=lane>>3, c=lane&7).
// ---------------------------------------------------------------------------
__global__ __launch_bounds__(256, 4) void k_out(
    const ushort4* __restrict__ u2v, const ushort4* __restrict__ v2v, // [NN*8]
    const int* __restrict__ src, const int* __restrict__ dst,
    const float* __restrict__ dists, const float* __restrict__ wp2,
    const float* __restrict__ bp2, float* __restrict__ out)
{
    int tid = threadIdx.x;
    int wv = __builtin_amdgcn_readfirstlane(tid >> 6);
    int lane = tid & 63;
    int c = lane & 7;       // dims 4c..4c+3
    int es = lane >> 3;     // edge subgroup 0..7 (k = es*4 + kk)
    int slot = blockIdx.x * 4 + wv;
    int stride = gridDim.x * 4;
    float4 w4 = reinterpret_cast<const float4*>(wp2)[c];
    float bp = bp2[0];
    const int nPairs = NN / 2;
    for (int p = slot; p < nPairs; p += stride) {
        int nA = p * 2, nB = nA + 1;
        int baseA = nA * KANCH, baseB = nB * KANCH;
        int4   sA = *reinterpret_cast<const int4*>(src + baseA + es * 4);
        int4   dA = *reinterpret_cast<const int4*>(dst + baseA + es * 4);
        float4 pA = *reinterpret_cast<const float4*>(dists + baseA + es * 4);
        int4   sB = *reinterpret_cast<const int4*>(src + baseB + es * 4);
        int4   dB = *reinterpret_cast<const int4*>(dst + baseB + es * 4);
        float4 pB = *reinterpret_cast<const float4*>(dists + baseB + es * 4);
        ushort4 uA[4], vA[4], uB[4], vB[4];
        uA[0] = u2v[(size_t)sA.x * 8 + c]; uA[1] = u2v[(size_t)sA.y * 8 + c];
        uA[2] = u2v[(size_t)sA.z * 8 + c]; uA[3] = u2v[(size_t)sA.w * 8 + c];
        vA[0] = v2v[(size_t)dA.x * 8 + c]; vA[1] = v2v[(size_t)dA.y * 8 + c];
        vA[2] = v2v[(size_t)dA.z * 8 + c]; vA[3] = v2v[(size_t)dA.w * 8 + c];
        uB[0] = u2v[(size_t)sB.x * 8 + c]; uB[1] = u2v[(size_t)sB.y * 8 + c];
        uB[2] = u2v[(size_t)sB.z * 8 + c]; uB[3] = u2v[(size_t)sB.w * 8 + c];
        vB[0] = v2v[(size_t)dB.x * 8 + c]; vB[1] = v2v[(size_t)dB.y * 8 + c];
        vB[2] = v2v[(size_t)dB.z * 8 + c]; vB[3] = v2v[(size_t)dB.w * 8 + c];
        float spA[4] = {pA.x, pA.y, pA.z, pA.w};
        float spB[4] = {pB.x, pB.y, pB.z, pB.w};
        float qA[4], qB[4];
#pragma unroll
        for (int kk = 0; kk < 4; ++kk) {
            float pa, pb;
            pa  = fmaxf(fmaf(bf2f(uA[kk].x), spA[kk], bf2f(vA[kk].x)), 0.f) * w4.x;
            pa += fmaxf(fmaf(bf2f(uA[kk].y), spA[kk], bf2f(vA[kk].y)), 0.f) * w4.y;
            pa += fmaxf(fmaf(bf2f(uA[kk].z), spA[kk], bf2f(vA[kk].z)), 0.f) * w4.z;
            pa += fmaxf(fmaf(bf2f(uA[kk].w), spA[kk], bf2f(vA[kk].w)), 0.f) * w4.w;
            pb  = fmaxf(fmaf(bf2f(uB[kk].x), spB[kk], bf2f(vB[kk].x)), 0.f) * w4.x;
            pb += fmaxf(fmaf(bf2f(uB[kk].y), spB[kk], bf2f(vB[kk].y)), 0.f) * w4.y;
            pb += fmaxf(fmaf(bf2f(uB[kk].z), spB[kk], bf2f(vB[kk].z)), 0.f) * w4.z;
            pb += fmaxf(fmaf(bf2f(uB[kk].w), spB[kk], bf2f(vB[kk].w)), 0.f) * w4.w;
            pa += __shfl_xor(pa, 1); pa += __shfl_xor(pa, 2); pa += __shfl_xor(pa, 4);
            pb += __shfl_xor(pb, 1); pb += __shfl_xor(pb, 2); pb += __shfl_xor(pb, 4);
            qA[kk] = pa; qB[kk] = pb;
        }
        int t = lane & 31;
        int srcl = (t >> 2) * 8;
        float cA0 = __shfl(qA[0], srcl), cA1 = __shfl(qA[1], srcl);
        float cA2 = __shfl(qA[2], srcl), cA3 = __shfl(qA[3], srcl);
        float cB0 = __shfl(qB[0], srcl), cB1 = __shfl(qB[1], srcl);
        float cB2 = __shfl(qB[2], srcl), cB3 = __shfl(qB[3], srcl);
        int ks = t & 3;
        float qa = (ks == 0) ? cA0 : (ks == 1) ? cA1 : (ks == 2) ? cA2 : cA3;
        float qb = (ks == 0) ? cB0 : (ks == 1) ? cB1 : (ks == 2) ? cB2 : cB3;
        float q = ((lane < 32) ? qa : qb) + bp;
        float ss = q * q;
#pragma unroll
        for (int off = 16; off >= 1; off >>= 1)
            ss += __shfl_xor(ss, off);     // stays within each 32-lane half
        float den = fmaxf(sqrtf(ss), 1e-12f);
        float o = q / den;
        if (lane < 32) out[(size_t)nA * KANCH + t] = o;
        else           out[(size_t)nB * KANCH + t] = o;
    }
}

// ---------------------------------------------------------------------------
extern "C" void kernel_launch(void* const* d_in, const int* in_sizes, int n_in,
                              void* d_out, int out_size, void* d_ws, size_t ws_size,
                              hipStream_t stream)
{
    const float* feat  = (const float*)d_in[0];
    const float* dists = (const float*)d_in[1];
    const int*   src   = (const int*)d_in[2];
    const int*   dst   = (const int*)d_in[3];
    const float* w_pre = (const float*)d_in[4];
    const float* b_pre = (const float*)d_in[5];
    const float* Wu1   = (const float*)d_in[6];
    const float* bu1   = (const float*)d_in[7];
    const float* Wv1   = (const float*)d_in[8];
    const float* bv1   = (const float*)d_in[9];
    // d_in[10]=wp1, d_in[11]=bp1: layer-1 position output is discarded
    const float* Wu2   = (const float*)d_in[12];
    const float* bu2   = (const float*)d_in[13];
    const float* Wv2   = (const float*)d_in[14];
    const float* bv2   = (const float*)d_in[15];
    const float* wp2   = (const float*)d_in[16];
    const float* bp2   = (const float*)d_in[17];
    float* out = (float*)d_out;

    // workspace (~19.3 MB)
    unsigned short* wcat1 = (unsigned short*)d_ws;           // 16384 us
    float* bias1 = (float*)(wcat1 + 16384);                  // 128 f
    unsigned short* u1b = (unsigned short*)(bias1 + 128);    // [NN][64]
    unsigned short* v1b = u1b + (size_t)NN * 64;             // [NN][64]
    unsigned short* u2b = v1b + (size_t)NN * 64;             // [NN][32]
    unsigned short* v2b = u2b + (size_t)NN * 32;             // [NN][32]

    k_prep<<<65, 256, 0, stream>>>(w_pre, b_pre, Wu1, bu1, Wv1, bv1,
                                   wcat1, bias1);
    k_gemm1<<<782, 256, 0, stream>>>(feat, wcat1, bias1, u1b, v1b, NN / 16);
    k_fuse<<<2048, 256, 0, stream>>>((const ushort4*)u1b, (const ushort4*)v1b,
                                     src, dst, dists,
                                     Wu2, bu2, Wv2, bv2, u2b, v2b);
    k_out<<<2048, 256, 0, stream>>>((const ushort4*)u2b, (const ushort4*)v2b,
                                    src, dst, dists, wp2, bp2, out);
}

// Round 8
// 110.238 us; speedup vs baseline: 1.3928x; 1.0671x over previous
//
#include <hip/hip_runtime.h>

// PGNN: N=50000 nodes, K=32 anchors/edges per node, E=1.6M edges
// out: normalize(out_position)[N,32] f32
constexpr int NN = 50000;
constexpr int KANCH = 32;

typedef __attribute__((ext_vector_type(8))) short bfrag;   // 8 bf16 (4 VGPR)
typedef __attribute__((ext_vector_type(4))) float ffrag;   // 4 f32 acc

static __device__ __forceinline__ float bf2f(unsigned short u) {
    return __uint_as_float(((unsigned int)u) << 16);
}
static __device__ __forceinline__ unsigned short f2bf(float f) {
    unsigned int x = __float_as_uint(f);
    x += 0x7FFFu + ((x >> 16) & 1u);   // round-to-nearest-even
    return (unsigned short)(x >> 16);
}

// ---------------------------------------------------------------------------
// K0: compose layer-1 weights through the pre-linear; pack weights to bf16.
// wcat1[j][i] = bf16((Wu1|Wv1)@w_pre) [128][128]; bias1 = (Wu1|Wv1)@b_pre+b
// wcat2[j][i] = bf16(Wu2|Wv2) [64][64]
// ---------------------------------------------------------------------------
__global__ __launch_bounds__(256) void k_prep(
    const float* __restrict__ w_pre, const float* __restrict__ b_pre,
    const float* __restrict__ Wu1, const float* __restrict__ bu1,
    const float* __restrict__ Wv1, const float* __restrict__ bv1,
    const float* __restrict__ Wu2, const float* __restrict__ Wv2,
    unsigned short* __restrict__ wcat1, float* __restrict__ bias1,
    unsigned short* __restrict__ wcat2)
{
    int gid = blockIdx.x * 256 + threadIdx.x;
    if (gid < 16384) {
        int j = gid >> 7, i = gid & 127;
        const float* Wr = (j < 64) ? (Wu1 + j * 64) : (Wv1 + (j - 64) * 64);
        float a = 0.f;
        for (int t = 0; t < 64; ++t) a += Wr[t] * w_pre[t * 128 + i];
        wcat1[gid] = f2bf(a);
    } else if (gid < 16384 + 4096) {
        int g = gid - 16384;
        int j = g >> 6, i = g & 63;
        float w = (j < 32) ? Wu2[j * 64 + i] : Wv2[(j - 32) * 64 + i];
        wcat2[g] = f2bf(w);
    } else if (gid < 16384 + 4096 + 128) {
        int j = gid - (16384 + 4096);
        const float* Wr = (j < 64) ? (Wu1 + j * 64) : (Wv1 + (j - 64) * 64);
        float a = (j < 64) ? bu1[j] : bv1[j - 64];
        for (int t = 0; t < 64; ++t) a += Wr[t] * b_pre[t];
        bias1[j] = a;
    }
}

// ---------------------------------------------------------------------------
// K1: layer-1 u/v linears via MFMA.  [NN][64] bf16 tables (round-5 verified).
// A (feat f32) split in-register into bf16 hi+lo (exact; 2 MFMAs per step).
// ---------------------------------------------------------------------------
__global__ __launch_bounds__(256) void k_gemm1(
    const float* __restrict__ feat,            // [NN][128]
    const unsigned short* __restrict__ wcat,   // [128][128] bf16
    const float* __restrict__ bias,            // [128] f32
    unsigned short* __restrict__ ub,           // [NN][64] bf16
    unsigned short* __restrict__ vb,           // [NN][64] bf16
    int nTiles)                                // NN/16
{
    __shared__ unsigned short s_w[128 * 136];  // 272 B row stride
    __shared__ float s_b[128];
    int tid = threadIdx.x;
    for (int idx = tid; idx < 128 * 16; idx += 256) {
        int r = idx >> 4, c8 = idx & 15;
        const uint4* g = reinterpret_cast<const uint4*>(wcat + r * 128 + c8 * 8);
        *reinterpret_cast<uint4*>(&s_w[r * 136 + c8 * 8]) = *g;
    }
    if (tid < 128) s_b[tid] = bias[tid];
    __syncthreads();

    int wv = __builtin_amdgcn_readfirstlane(tid >> 6);
    int lane = tid & 63;
    int col = lane & 15;        // A row (node) / D col (out) / W row
    int grp = lane >> 4;        // k-subchunk 0..3
    int slot = blockIdx.x * 4 + wv;
    int stride = gridDim.x * 4;
    for (int tile = slot; tile < nTiles; tile += stride) {
        int n0 = tile * 16;
        const float* fp = feat + (size_t)(n0 + col) * 128 + grp * 8;
        bfrag AH[4], AL[4];
#pragma unroll
        for (int s = 0; s < 4; ++s) {
            float4 p0 = *reinterpret_cast<const float4*>(fp + s * 32);
            float4 p1 = *reinterpret_cast<const float4*>(fp + s * 32 + 4);
            float a8[8] = {p0.x, p0.y, p0.z, p0.w, p1.x, p1.y, p1.z, p1.w};
#pragma unroll
            for (int e = 0; e < 8; ++e) {
                unsigned short hb = f2bf(a8[e]);
                AH[s][e] = (short)hb;
                AL[s][e] = (short)f2bf(a8[e] - bf2f(hb));
            }
        }
#pragma unroll
        for (int t = 0; t < 8; ++t) {
            ffrag a = {0.f, 0.f, 0.f, 0.f};
#pragma unroll
            for (int s = 0; s < 4; ++s) {
                const bfrag w = *reinterpret_cast<const bfrag*>(
                    &s_w[(t * 16 + col) * 136 + s * 32 + grp * 8]);
                a = __builtin_amdgcn_mfma_f32_16x16x32_bf16(AH[s], w, a, 0, 0, 0);
                a = __builtin_amdgcn_mfma_f32_16x16x32_bf16(AL[s], w, a, 0, 0, 0);
            }
            float bb = s_b[t * 16 + col];
#pragma unroll
            for (int j = 0; j < 4; ++j) {
                int node = n0 + grp * 4 + j;
                unsigned short o = f2bf(a[j] + bb);
                if (t < 4) ub[(size_t)node * 64 + t * 16 + col] = o;
                else       vb[(size_t)node * 64 + (t - 4) * 16 + col] = o;
            }
        }
    }
}

// ---------------------------------------------------------------------------
// K2: FUSED layer-1 aggregation + layer-2 linears via MFMA.
// Wave batch = 8 nodes. Per node: round-5 gather (es-major int4 index loads,
// 16 ushort4 table loads, shfl reduce), x2 -> bf16x4 ds_write into a
// wave-private LDS tile [8][72] (144B stride, 16B-aligned b128 reads).
// After 8 nodes: 2 ds_read_b128 A-frags + 8 MFMA vs preloaded wcat2 B-frags
// (the 16-row MFMA's rows 8-15 are garbage and never written).
// Replaces k_gemm2 entirely: no x2 global round-trip, no extra dispatch.
// ---------------------------------------------------------------------------
__global__ __launch_bounds__(256) void k_fuse2(
    const ushort4* __restrict__ u1v, const ushort4* __restrict__ v1v, // [NN*16]
    const int* __restrict__ src, const int* __restrict__ dst,
    const float* __restrict__ dists,
    const unsigned short* __restrict__ wcat2,  // [64][64] bf16
    const float* __restrict__ bu2, const float* __restrict__ bv2,
    unsigned short* __restrict__ u2b,          // [NN][32] bf16
    unsigned short* __restrict__ v2b)          // [NN][32] bf16
{
    __shared__ unsigned short s_x2[4][16 * 72];   // per-wave [node][72] tile
    int tid = threadIdx.x;
    int wv = __builtin_amdgcn_readfirstlane(tid >> 6);
    int lane = tid & 63;
    int c = lane & 15;      // gather: dim chunk / MFMA: col
    int es = lane >> 4;     // gather: edge subgroup / MFMA: k-group
    // ---- one-time: preload B-fragments of W2cat and bias ----
    bfrag Bf[4][2];
#pragma unroll
    for (int t = 0; t < 4; ++t)
#pragma unroll
        for (int s = 0; s < 2; ++s) {
            uint4 raw = *reinterpret_cast<const uint4*>(
                wcat2 + (t * 16 + c) * 64 + s * 32 + es * 8);
            Bf[t][s] = *reinterpret_cast<const bfrag*>(&raw);
        }
    float bb[4];
#pragma unroll
    for (int t = 0; t < 4; ++t)
        bb[t] = (t < 2) ? bu2[t * 16 + c] : bv2[(t - 2) * 16 + c];

    unsigned short* sx = &s_x2[wv][0];
    int slot = blockIdx.x * 4 + wv;
    int stride = gridDim.x * 4;
    const int nBatch = NN / 8;            // 6250
    for (int b = slot; b < nBatch; b += stride) {
        int n0 = b * 8;
        // ---- gather phase: 8 nodes, x2 rows -> LDS tile ----
        for (int i = 0; i < 8; ++i) {
            int base = (n0 + i) * KANCH + es * 8;
            int4   si0 = *reinterpret_cast<const int4*>(src + base);
            int4   si1 = *reinterpret_cast<const int4*>(src + base + 4);
            int4   di0 = *reinterpret_cast<const int4*>(dst + base);
            int4   di1 = *reinterpret_cast<const int4*>(dst + base + 4);
            float4 pp0 = *reinterpret_cast<const float4*>(dists + base);
            float4 pp1 = *reinterpret_cast<const float4*>(dists + base + 4);
            ushort4 uu[8], vvv[8];
            uu[0] = u1v[(size_t)si0.x * 16 + c]; uu[1] = u1v[(size_t)si0.y * 16 + c];
            uu[2] = u1v[(size_t)si0.z * 16 + c]; uu[3] = u1v[(size_t)si0.w * 16 + c];
            uu[4] = u1v[(size_t)si1.x * 16 + c]; uu[5] = u1v[(size_t)si1.y * 16 + c];
            uu[6] = u1v[(size_t)si1.z * 16 + c]; uu[7] = u1v[(size_t)si1.w * 16 + c];
            vvv[0] = v1v[(size_t)di0.x * 16 + c]; vvv[1] = v1v[(size_t)di0.y * 16 + c];
            vvv[2] = v1v[(size_t)di0.z * 16 + c]; vvv[3] = v1v[(size_t)di0.w * 16 + c];
            vvv[4] = v1v[(size_t)di1.x * 16 + c]; vvv[5] = v1v[(size_t)di1.y * 16 + c];
            vvv[6] = v1v[(size_t)di1.z * 16 + c]; vvv[7] = v1v[(size_t)di1.w * 16 + c];
            float sp[8] = {pp0.x, pp0.y, pp0.z, pp0.w, pp1.x, pp1.y, pp1.z, pp1.w};
            float a0 = 0.f, a1 = 0.f, a2 = 0.f, a3 = 0.f;
#pragma unroll
            for (int kk = 0; kk < 8; ++kk) {
                a0 += fmaxf(fmaf(bf2f(uu[kk].x), sp[kk], bf2f(vvv[kk].x)), 0.f);
                a1 += fmaxf(fmaf(bf2f(uu[kk].y), sp[kk], bf2f(vvv[kk].y)), 0.f);
                a2 += fmaxf(fmaf(bf2f(uu[kk].z), sp[kk], bf2f(vvv[kk].z)), 0.f);
                a3 += fmaxf(fmaf(bf2f(uu[kk].w), sp[kk], bf2f(vvv[kk].w)), 0.f);
            }
            a0 += __shfl_xor(a0, 16); a0 += __shfl_xor(a0, 32);
            a1 += __shfl_xor(a1, 16); a1 += __shfl_xor(a1, 32);
            a2 += __shfl_xor(a2, 16); a2 += __shfl_xor(a2, 32);
            a3 += __shfl_xor(a3, 16); a3 += __shfl_xor(a3, 32);
            if (lane < 16) {
                ushort4 r;
                r.x = f2bf(a0 * 0.03125f); r.y = f2bf(a1 * 0.03125f);
                r.z = f2bf(a2 * 0.03125f); r.w = f2bf(a3 * 0.03125f);
                *reinterpret_cast<ushort4*>(&sx[i * 72 + c * 4]) = r;
            }
        }
        // ---- MFMA phase: x2 tile @ W2cat^T -> u2/v2 rows ----
        bfrag A[2];
#pragma unroll
        for (int s = 0; s < 2; ++s)
            A[s] = *reinterpret_cast<const bfrag*>(
                &sx[(lane & 15) * 72 + s * 32 + es * 8]);
        ffrag acc[4];
#pragma unroll
        for (int t = 0; t < 4; ++t) {
            acc[t] = ffrag{0.f, 0.f, 0.f, 0.f};
#pragma unroll
            for (int s = 0; s < 2; ++s)
                acc[t] = __builtin_amdgcn_mfma_f32_16x16x32_bf16(
                    A[s], Bf[t][s], acc[t], 0, 0, 0);
        }
        if (es < 2) {                      // rows 0..7 are the real nodes
#pragma unroll
            for (int t = 0; t < 4; ++t) {
#pragma unroll
                for (int j = 0; j < 4; ++j) {
                    int node = n0 + es * 4 + j;
                    unsigned short o = f2bf(acc[t][j] + bb[t]);
                    if (t < 2) u2b[(size_t)node * 32 + t * 16 + c] = o;
                    else       v2b[(size_t)node * 32 + (t - 2) * 16 + c] = o;
                }
            }
        }
    }
}

// ---------------------------------------------------------------------------
// K3: layer-2 message + position dot + L2 normalize (round-5 verified).
// Wave handles TWO nodes per iter; lane = (es=lane>>3, c=lane&7).
// ---------------------------------------------------------------------------
__global__ __launch_bounds__(256, 4) void k_out(
    const ushort4* __restrict__ u2v, const ushort4* __restrict__ v2v, // [NN*8]
    const int* __restrict__ src, const int* __restrict__ dst,
    const float* __restrict__ dists, const float* __restrict__ wp2,
    const float* __restrict__ bp2, float* __restrict__ out)
{
    int tid = threadIdx.x;
    int wv = __builtin_amdgcn_readfirstlane(tid >> 6);
    int lane = tid & 63;
    int c = lane & 7;       // dims 4c..4c+3
    int es = lane >> 3;     // edge subgroup 0..7 (k = es*4 + kk)
    int slot = blockIdx.x * 4 + wv;
    int stride = gridDim.x * 4;
    float4 w4 = reinterpret_cast<const float4*>(wp2)[c];
    float bp = bp2[0];
    const int nPairs = NN / 2;
    for (int p = slot; p < nPairs; p += stride) {
        int nA = p * 2, nB = nA + 1;
        int baseA = nA * KANCH, baseB = nB * KANCH;
        int4   sA = *reinterpret_cast<const int4*>(src + baseA + es * 4);
        int4   dA = *reinterpret_cast<const int4*>(dst + baseA + es * 4);
        float4 pA = *reinterpret_cast<const float4*>(dists + baseA + es * 4);
        int4   sB = *reinterpret_cast<const int4*>(src + baseB + es * 4);
        int4   dB = *reinterpret_cast<const int4*>(dst + baseB + es * 4);
        float4 pB = *reinterpret_cast<const float4*>(dists + baseB + es * 4);
        ushort4 uA[4], vA[4], uB[4], vB[4];
        uA[0] = u2v[(size_t)sA.x * 8 + c]; uA[1] = u2v[(size_t)sA.y * 8 + c];
        uA[2] = u2v[(size_t)sA.z * 8 + c]; uA[3] = u2v[(size_t)sA.w * 8 + c];
        vA[0] = v2v[(size_t)dA.x * 8 + c]; vA[1] = v2v[(size_t)dA.y * 8 + c];
        vA[2] = v2v[(size_t)dA.z * 8 + c]; vA[3] = v2v[(size_t)dA.w * 8 + c];
        uB[0] = u2v[(size_t)sB.x * 8 + c]; uB[1] = u2v[(size_t)sB.y * 8 + c];
        uB[2] = u2v[(size_t)sB.z * 8 + c]; uB[3] = u2v[(size_t)sB.w * 8 + c];
        vB[0] = v2v[(size_t)dB.x * 8 + c]; vB[1] = v2v[(size_t)dB.y * 8 + c];
        vB[2] = v2v[(size_t)dB.z * 8 + c]; vB[3] = v2v[(size_t)dB.w * 8 + c];
        float spA[4] = {pA.x, pA.y, pA.z, pA.w};
        float spB[4] = {pB.x, pB.y, pB.z, pB.w};
        float qA[4], qB[4];
#pragma unroll
        for (int kk = 0; kk < 4; ++kk) {
            float pa, pb;
            pa  = fmaxf(fmaf(bf2f(uA[kk].x), spA[kk], bf2f(vA[kk].x)), 0.f) * w4.x;
            pa += fmaxf(fmaf(bf2f(uA[kk].y), spA[kk], bf2f(vA[kk].y)), 0.f) * w4.y;
            pa += fmaxf(fmaf(bf2f(uA[kk].z), spA[kk], bf2f(vA[kk].z)), 0.f) * w4.z;
            pa += fmaxf(fmaf(bf2f(uA[kk].w), spA[kk], bf2f(vA[kk].w)), 0.f) * w4.w;
            pb  = fmaxf(fmaf(bf2f(uB[kk].x), spB[kk], bf2f(vB[kk].x)), 0.f) * w4.x;
            pb += fmaxf(fmaf(bf2f(uB[kk].y), spB[kk], bf2f(vB[kk].y)), 0.f) * w4.y;
            pb += fmaxf(fmaf(bf2f(uB[kk].z), spB[kk], bf2f(vB[kk].z)), 0.f) * w4.z;
            pb += fmaxf(fmaf(bf2f(uB[kk].w), spB[kk], bf2f(vB[kk].w)), 0.f) * w4.w;
            pa += __shfl_xor(pa, 1); pa += __shfl_xor(pa, 2); pa += __shfl_xor(pa, 4);
            pb += __shfl_xor(pb, 1); pb += __shfl_xor(pb, 2); pb += __shfl_xor(pb, 4);
            qA[kk] = pa; qB[kk] = pb;
        }
        int t = lane & 31;
        int srcl = (t >> 2) * 8;
        float cA0 = __shfl(qA[0], srcl), cA1 = __shfl(qA[1], srcl);
        float cA2 = __shfl(qA[2], srcl), cA3 = __shfl(qA[3], srcl);
        float cB0 = __shfl(qB[0], srcl), cB1 = __shfl(qB[1], srcl);
        float cB2 = __shfl(qB[2], srcl), cB3 = __shfl(qB[3], srcl);
        int ks = t & 3;
        float qa = (ks == 0) ? cA0 : (ks == 1) ? cA1 : (ks == 2) ? cA2 : cA3;
        float qb = (ks == 0) ? cB0 : (ks == 1) ? cB1 : (ks == 2) ? cB2 : cB3;
        float q = ((lane < 32) ? qa : qb) + bp;
        float ss = q * q;
#pragma unroll
        for (int off = 16; off >= 1; off >>= 1)
            ss += __shfl_xor(ss, off);     // stays within each 32-lane half
        float den = fmaxf(sqrtf(ss), 1e-12f);
        float o = q / den;
        if (lane < 32) out[(size_t)nA * KANCH + t] = o;
        else           out[(size_t)nB * KANCH + t] = o;
    }
}

// ---------------------------------------------------------------------------
extern "C" void kernel_launch(void* const* d_in, const int* in_sizes, int n_in,
                              void* d_out, int out_size, void* d_ws, size_t ws_size,
                              hipStream_t stream)
{
    const float* feat  = (const float*)d_in[0];
    const float* dists = (const float*)d_in[1];
    const int*   src   = (const int*)d_in[2];
    const int*   dst   = (const int*)d_in[3];
    const float* w_pre = (const float*)d_in[4];
    const float* b_pre = (const float*)d_in[5];
    const float* Wu1   = (const float*)d_in[6];
    const float* bu1   = (const float*)d_in[7];
    const float* Wv1   = (const float*)d_in[8];
    const float* bv1   = (const float*)d_in[9];
    // d_in[10]=wp1, d_in[11]=bp1: layer-1 position output is discarded
    const float* Wu2   = (const float*)d_in[12];
    const float* bu2   = (const float*)d_in[13];
    const float* Wv2   = (const float*)d_in[14];
    const float* bv2   = (const float*)d_in[15];
    const float* wp2   = (const float*)d_in[16];
    const float* bp2   = (const float*)d_in[17];
    float* out = (float*)d_out;

    // workspace (~19.2 MB)
    unsigned short* wcat1 = (unsigned short*)d_ws;           // 16384 us
    float* bias1 = (float*)(wcat1 + 16384);                  // 128 f
    unsigned short* wcat2 = (unsigned short*)(bias1 + 128);  // 4096 us
    unsigned short* u1b = wcat2 + 4096;                      // [NN][64]
    unsigned short* v1b = u1b + (size_t)NN * 64;             // [NN][64]
    unsigned short* u2b = v1b + (size_t)NN * 64;             // [NN][32]
    unsigned short* v2b = u2b + (size_t)NN * 32;             // [NN][32]

    k_prep<<<81, 256, 0, stream>>>(w_pre, b_pre, Wu1, bu1, Wv1, bv1,
                                   Wu2, Wv2, wcat1, bias1, wcat2);
    k_gemm1<<<782, 256, 0, stream>>>(feat, wcat1, bias1, u1b, v1b, NN / 16);
    k_fuse2<<<1563, 256, 0, stream>>>((const ushort4*)u1b, (const ushort4*)v1b,
                                      src, dst, dists, wcat2, bu2, bv2,
                                      u2b, v2b);
    k_out<<<2048, 256, 0, stream>>>((const ushort4*)u2b, (const ushort4*)v2b,
                                    src, dst, dists, wp2, bp2, out);
}